// Round 4
// baseline (99.280 us; speedup 1.0000x reference)
//
#include <hip/hip_runtime.h>

typedef float f32x4 __attribute__((ext_vector_type(4)));
typedef short short8 __attribute__((ext_vector_type(8)));

#define NTYPES 4

// ws layout (bytes):
//   [0,64)        meta ints: 0-3 counts, 4-7 cursors, 8-12 bases (bases[i]=meta[8+i])
//   [1024,...)    perm[ntiles*64] ints (pad slots = -1)
//   [402432,)     W1T bf16 [4][256][128]  (262144 B)   W1T[t][hcol][k]
//   [664576,)     W2T bf16 [4][128][256]  (262144 B)   W2T[t][ocol][h]
//   [1048576,)    Xs bf16, sorted+padded+tile-swizzled, ntiles*16384 B (~25.7MB)

static __device__ __forceinline__ unsigned short f2bf(float f) {
  union { float f; unsigned int u; } v; v.f = f;
  unsigned int u = v.u;
  unsigned int r = u + 0x7FFFu + ((u >> 16) & 1u);   // round-nearest-even
  return (unsigned short)(r >> 16);
}

__global__ __launch_bounds__(256) void k_prep(const float* __restrict__ W1,
                                              const float* __restrict__ W2,
                                              unsigned short* __restrict__ W1T,
                                              unsigned short* __restrict__ W2T) {
  int i = blockIdx.x * 256 + threadIdx.x;   // 0..131071
  int t = i >> 15, rem = i & 32767;
  {
    int c = rem >> 7, k = rem & 127;        // W1T[t][c][k] = W1[t][k][c]
    W1T[i] = f2bf(W1[(t << 15) + k * 256 + c]);
  }
  {
    int o = rem >> 8, h = rem & 255;        // W2T[t][o][h] = W2[t][h][o]
    W2T[i] = f2bf(W2[(t << 15) + h * 128 + o]);
  }
}

__global__ __launch_bounds__(256) void k_hist(const int* __restrict__ NT, int n,
                                              int* __restrict__ meta) {
  __shared__ int c[NTYPES];
  if (threadIdx.x < NTYPES) c[threadIdx.x] = 0;
  __syncthreads();
  int i = blockIdx.x * 256 + threadIdx.x;
  if (i < n) atomicAdd(&c[NT[i]], 1);
  __syncthreads();
  if (threadIdx.x < NTYPES && c[threadIdx.x] > 0)
    atomicAdd(&meta[threadIdx.x], c[threadIdx.x]);
}

// scatter + inline prefix (from final counts) + base publish + pad fill
__global__ __launch_bounds__(256) void k_scatter(const int* __restrict__ NT, int n,
                                                 int* __restrict__ meta,
                                                 int* __restrict__ perm) {
  __shared__ int cnt[NTYPES];
  __shared__ int cbase[NTYPES];
  __shared__ int sb[NTYPES + 1];
  if (threadIdx.x < NTYPES) cnt[threadIdx.x] = 0;
  if (threadIdx.x == 0) {
    int b = 0; sb[0] = 0;
    for (int t = 0; t < NTYPES; ++t) {
      b += (meta[t] + 63) & ~63;           // pad each segment to 64
      sb[t + 1] = b;
    }
  }
  __syncthreads();
  int i = blockIdx.x * 256 + threadIdx.x;
  int t = 0, r = 0;
  bool valid = (i < n);
  if (valid) { t = NT[i]; r = atomicAdd(&cnt[t], 1); }
  __syncthreads();
  if (threadIdx.x < NTYPES)
    cbase[threadIdx.x] = atomicAdd(&meta[4 + threadIdx.x], cnt[threadIdx.x]);
  __syncthreads();
  if (valid) perm[sb[t] + cbase[t] + r] = i;
  if (blockIdx.x == 0) {
    if (threadIdx.x <= NTYPES) meta[8 + threadIdx.x] = sb[threadIdx.x];
    int tt = threadIdx.x >> 6, j = threadIdx.x & 63;   // pad count per type <= 63
    int p = sb[tt] + meta[tt] + j;
    if (p < sb[tt + 1]) perm[p] = -1;
  }
}

// Physically permute X -> Xs: bf16, sorted order, padded rows zeroed,
// tile-swizzled so k_mlp can global_load_lds LINEARLY and ds_read swizzled.
// Swizzle within 16KB tile: byte = (r*256 + chunk*16) ^ ((r&7)<<4)
__global__ __launch_bounds__(512) void k_sort(const float* __restrict__ X,
                                              const int* __restrict__ perm,
                                              const int* __restrict__ meta,
                                              unsigned short* __restrict__ Xs) {
  const int tid = threadIdx.x;
  const int r = tid >> 3;            // sorted row within tile, 0..63
  const int c = tid & 7;             // chunk group
  const int p = blockIdx.x * 64 + r;
  if (p >= meta[12]) return;
  const int rid = perm[p];
  char* xt = (char*)(Xs + (size_t)blockIdx.x * 8192);
  #pragma unroll
  for (int q = 0; q < 2; ++q) {
    int cc = c + q * 8;              // 16B-chunk index 0..15 (8 bf16)
    short8 u = {0, 0, 0, 0, 0, 0, 0, 0};
    if (rid >= 0) {
      const float* src = X + (size_t)rid * 128 + cc * 8;
      float4 v0 = *(const float4*)(src);
      float4 v1 = *(const float4*)(src + 4);
      u[0] = (short)f2bf(v0.x); u[1] = (short)f2bf(v0.y);
      u[2] = (short)f2bf(v0.z); u[3] = (short)f2bf(v0.w);
      u[4] = (short)f2bf(v1.x); u[5] = (short)f2bf(v1.y);
      u[6] = (short)f2bf(v1.z); u[7] = (short)f2bf(v1.w);
    }
    int byte = (r * 256 + cc * 16) ^ ((r & 7) << 4);
    *(short8*)(xt + byte) = u;
  }
}

// Fused MLP on one 64-node type-uniform tile, 8 waves (512 thr).
// Transposed MFMAs: mfma(W_frag as A, x_frag as B) -> lane holds 4 consecutive
// OUTPUT columns -> packed b64 h-writes and dwordx4 OUT stores.
__global__ __launch_bounds__(512) void k_mlp(
    const unsigned short* __restrict__ Xs, const int* __restrict__ perm,
    const int* __restrict__ meta,
    const unsigned short* __restrict__ W1T, const unsigned short* __restrict__ W2T,
    const float* __restrict__ B1, const float* __restrict__ B2,
    float* __restrict__ OUT) {
  __shared__ __align__(16) unsigned char x_lds[64 * 256];   // 16KB bf16 (pre-swizzled)
  __shared__ __align__(16) unsigned char h_lds[64 * 512];   // 32KB bf16 (swizzled)
  __shared__ int s_rowid[64];

  const int tid = threadIdx.x;
  const int ntile = meta[12] >> 6;
  const int ti = blockIdx.x;
  if (ti >= ntile) return;
  const int ts = ti * 64;
  int t = 0;
  if (ts >= meta[9])  t = 1;
  if (ts >= meta[10]) t = 2;
  if (ts >= meta[11]) t = 3;

  // ---- stage: global_load_lds, linear copy (data already bf16+swizzled) ----
  {
    const int w = tid >> 6, l = tid & 63;
    const unsigned short* s0 = Xs + (size_t)ti * 8192 + w * 512 + l * 8;
    __builtin_amdgcn_global_load_lds(
        (const __attribute__((address_space(1))) unsigned int*)s0,
        (__attribute__((address_space(3))) unsigned int*)(x_lds + w * 1024),
        16, 0, 0);
    __builtin_amdgcn_global_load_lds(
        (const __attribute__((address_space(1))) unsigned int*)(s0 + 4096),
        (__attribute__((address_space(3))) unsigned int*)(x_lds + w * 1024 + 8192),
        16, 0, 0);
  }
  if (tid < 64) s_rowid[tid] = perm[ts + tid];
  __syncthreads();

  const int l  = tid & 63;
  const int w  = tid >> 6;    // wave 0..7
  const int lo = l & 15;
  const int hi = l >> 4;
  const int wm = w >> 2;      // node half 0/1
  const int wn = w & 3;       // col group 0..3
  const int rb = wm * 32;     // node base
  const int c0 = wn * 64;     // hidden-col base

  // ---- layer 1 (transposed): acc[hfrag m][nodefrag n] = W1T x^T ----
  f32x4 acc[4][2];
  #pragma unroll
  for (int m = 0; m < 4; ++m)
    #pragma unroll
    for (int n = 0; n < 2; ++n) acc[m][n] = (f32x4){0.f, 0.f, 0.f, 0.f};

  const unsigned short* w1t = W1T + (t << 15);
  #pragma unroll
  for (int ks = 0; ks < 4; ++ks) {
    const int k8 = ks * 32 + hi * 8;
    short8 a[4];
    #pragma unroll
    for (int m = 0; m < 4; ++m) {           // A = W1T[hcol][k]
      int col = c0 + m * 16 + lo;
      a[m] = *(const short8*)(w1t + col * 128 + k8);
    }
    short8 b[2];
    #pragma unroll
    for (int n = 0; n < 2; ++n) {           // B[k][node] = X[node][k]
      int row = rb + n * 16 + lo;
      int byte = (row * 256 + k8 * 2) ^ ((row & 7) << 4);
      b[n] = *(const short8*)(x_lds + byte);
    }
    #pragma unroll
    for (int m = 0; m < 4; ++m)
      #pragma unroll
      for (int n = 0; n < 2; ++n)
        acc[m][n] = __builtin_amdgcn_mfma_f32_16x16x32_bf16(a[m], b[n], acc[m][n], 0, 0, 0);
  }

  // bias + relu + h -> LDS: lane holds 4 consecutive hidden cols -> b64 writes
  #pragma unroll
  for (int m = 0; m < 4; ++m) {
    int hc = c0 + m * 16 + hi * 4;
    float4 bb = *(const float4*)(B1 + t * 256 + hc);
    #pragma unroll
    for (int n = 0; n < 2; ++n) {
      int row = rb + n * 16 + lo;
      ushort4 hv;
      hv.x = f2bf(fmaxf(acc[m][n][0] + bb.x, 0.f));
      hv.y = f2bf(fmaxf(acc[m][n][1] + bb.y, 0.f));
      hv.z = f2bf(fmaxf(acc[m][n][2] + bb.z, 0.f));
      hv.w = f2bf(fmaxf(acc[m][n][3] + bb.w, 0.f));
      int byte = (row * 512 + hc * 2) ^ ((row & 7) << 4);
      *(ushort4*)(h_lds + byte) = hv;
    }
  }
  __syncthreads();

  // ---- layer 2 (transposed): acc2[ofrag m][nodefrag n] = W2T h^T ----
  f32x4 acc2[2][2];
  #pragma unroll
  for (int m = 0; m < 2; ++m)
    #pragma unroll
    for (int n = 0; n < 2; ++n) acc2[m][n] = (f32x4){0.f, 0.f, 0.f, 0.f};

  const int o0 = wn * 32;
  const unsigned short* w2t = W2T + (t << 15);
  #pragma unroll
  for (int ks = 0; ks < 8; ++ks) {
    const int k8 = ks * 32 + hi * 8;
    short8 a[2];
    #pragma unroll
    for (int m = 0; m < 2; ++m) {           // A = W2T[ocol][h]
      int col = o0 + m * 16 + lo;
      a[m] = *(const short8*)(w2t + col * 256 + k8);
    }
    short8 b[2];
    #pragma unroll
    for (int n = 0; n < 2; ++n) {           // B[h][node] = h[node][h]
      int row = rb + n * 16 + lo;
      int byte = (row * 512 + k8 * 2) ^ ((row & 7) << 4);
      b[n] = *(const short8*)(h_lds + byte);
    }
    #pragma unroll
    for (int m = 0; m < 2; ++m)
      #pragma unroll
      for (int n = 0; n < 2; ++n)
        acc2[m][n] = __builtin_amdgcn_mfma_f32_16x16x32_bf16(a[m], b[n], acc2[m][n], 0, 0, 0);
  }

  // epilogue: lane holds 4 consecutive out cols -> one dwordx4 store per frag
  #pragma unroll
  for (int m = 0; m < 2; ++m) {
    int oc = o0 + m * 16 + hi * 4;
    float4 bb = *(const float4*)(B2 + t * 128 + oc);
    #pragma unroll
    for (int n = 0; n < 2; ++n) {
      int row = rb + n * 16 + lo;
      int rid = s_rowid[row];
      if (rid >= 0) {
        float4 o;
        o.x = acc2[m][n][0] + bb.x;
        o.y = acc2[m][n][1] + bb.y;
        o.z = acc2[m][n][2] + bb.z;
        o.w = acc2[m][n][3] + bb.w;
        *(float4*)(OUT + (size_t)rid * 128 + oc) = o;
      }
    }
  }
}

extern "C" void kernel_launch(void* const* d_in, const int* in_sizes, int n_in,
                              void* d_out, int out_size, void* d_ws, size_t ws_size,
                              hipStream_t stream) {
  const float* X  = (const float*)d_in[0];
  const int*   NT = (const int*)d_in[1];
  const float* W1 = (const float*)d_in[2];
  const float* B1 = (const float*)d_in[3];
  const float* W2 = (const float*)d_in[4];
  const float* B2 = (const float*)d_in[5];
  float* OUT = (float*)d_out;
  const int n = in_sizes[1];

  char* ws = (char*)d_ws;
  int* meta = (int*)ws;                                   // counts/cursors/bases
  int* perm = (int*)(ws + 1024);
  unsigned short* W1T = (unsigned short*)(ws + 402432);
  unsigned short* W2T = (unsigned short*)(ws + 664576);
  unsigned short* Xs  = (unsigned short*)(ws + 1048576);

  const int ntiles = (n + 63) / 64 + NTYPES;              // worst-case padded tiles

  hipMemsetAsync(ws, 0, 64, stream);                      // counts + cursors = 0

  k_prep<<<512, 256, 0, stream>>>(W1, W2, W1T, W2T);
  const int nb = (n + 255) / 256;
  k_hist<<<nb, 256, 0, stream>>>(NT, n, meta);
  k_scatter<<<nb, 256, 0, stream>>>(NT, n, meta, perm);
  k_sort<<<ntiles, 512, 0, stream>>>(X, perm, meta, Xs);
  k_mlp<<<ntiles, 512, 0, stream>>>(Xs, perm, meta, W1T, W2T, B1, B2, OUT);
}

// Round 5
// 73.513 us; speedup vs baseline: 1.3505x; 1.3505x over previous
//
#include <hip/hip_runtime.h>

typedef float f32x4 __attribute__((ext_vector_type(4)));
typedef short short8 __attribute__((ext_vector_type(8)));

#define NTYPES 4

// ws layout (bytes):
//   [0,64)        meta ints: 0-3 counts, 4-7 cursors, 8-12 bases (bases[i]=meta[8+i])
//   [512,1024)    dump row (pad-node store sink)
//   [1024,...)    perm[ntiles*64] ints (pad slots = -1)
//   [402432,)     W1T bf16 [4][256][128]  W1T[t][hcol][k]
//   [664576,)     W2T bf16 [4][128][256]  W2T[t][ocol][h]
//   [1048576,)    Xs bf16, sorted+padded+tile-swizzled, ntiles*16384 B

static __device__ __forceinline__ unsigned short f2bf(float f) {
  union { float f; unsigned int u; } v; v.f = f;
  unsigned int u = v.u;
  unsigned int r = u + 0x7FFFu + ((u >> 16) & 1u);   // round-nearest-even
  return (unsigned short)(r >> 16);
}

#define LGKM_BAR() do { \
  asm volatile("s_waitcnt lgkmcnt(0)" ::: "memory"); \
  __builtin_amdgcn_s_barrier(); \
  __builtin_amdgcn_sched_barrier(0); } while (0)

__global__ __launch_bounds__(256) void k_prep(const float* __restrict__ W1,
                                              const float* __restrict__ W2,
                                              unsigned short* __restrict__ W1T,
                                              unsigned short* __restrict__ W2T) {
  int i = blockIdx.x * 256 + threadIdx.x;   // 0..131071
  int t = i >> 15, rem = i & 32767;
  {
    int c = rem >> 7, k = rem & 127;        // W1T[t][c][k] = W1[t][k][c]
    W1T[i] = f2bf(W1[(t << 15) + k * 256 + c]);
  }
  {
    int o = rem >> 8, h = rem & 255;        // W2T[t][o][h] = W2[t][h][o]
    W2T[i] = f2bf(W2[(t << 15) + h * 128 + o]);
  }
}

__global__ __launch_bounds__(256) void k_hist(const int* __restrict__ NT, int n,
                                              int* __restrict__ meta) {
  __shared__ int c[NTYPES];
  if (threadIdx.x < NTYPES) c[threadIdx.x] = 0;
  __syncthreads();
  int i = blockIdx.x * 256 + threadIdx.x;
  if (i < n) atomicAdd(&c[NT[i]], 1);
  __syncthreads();
  if (threadIdx.x < NTYPES && c[threadIdx.x] > 0)
    atomicAdd(&meta[threadIdx.x], c[threadIdx.x]);
}

// scatter + inline prefix (from final counts) + base publish + pad fill
__global__ __launch_bounds__(256) void k_scatter(const int* __restrict__ NT, int n,
                                                 int* __restrict__ meta,
                                                 int* __restrict__ perm) {
  __shared__ int cnt[NTYPES];
  __shared__ int cbase[NTYPES];
  __shared__ int sb[NTYPES + 1];
  if (threadIdx.x < NTYPES) cnt[threadIdx.x] = 0;
  if (threadIdx.x == 0) {
    int b = 0; sb[0] = 0;
    for (int t = 0; t < NTYPES; ++t) {
      b += (meta[t] + 63) & ~63;           // pad each segment to 64
      sb[t + 1] = b;
    }
  }
  __syncthreads();
  int i = blockIdx.x * 256 + threadIdx.x;
  int t = 0, r = 0;
  bool valid = (i < n);
  if (valid) { t = NT[i]; r = atomicAdd(&cnt[t], 1); }
  __syncthreads();
  if (threadIdx.x < NTYPES)
    cbase[threadIdx.x] = atomicAdd(&meta[4 + threadIdx.x], cnt[threadIdx.x]);
  __syncthreads();
  if (valid) perm[sb[t] + cbase[t] + r] = i;
  if (blockIdx.x == 0) {
    if (threadIdx.x <= NTYPES) meta[8 + threadIdx.x] = sb[threadIdx.x];
    int tt = threadIdx.x >> 6, j = threadIdx.x & 63;   // pad count per type <= 63
    int p = sb[tt] + meta[tt] + j;
    if (p < sb[tt + 1]) perm[p] = -1;
  }
}

// Physically permute X -> Xs: bf16, sorted order, padded rows zeroed,
// tile-swizzled: within 16KB tile, byte = (r*256 + chunk*16) ^ ((r&7)<<4)
__global__ __launch_bounds__(512) void k_sort(const float* __restrict__ X,
                                              const int* __restrict__ perm,
                                              const int* __restrict__ meta,
                                              unsigned short* __restrict__ Xs) {
  const int tid = threadIdx.x;
  const int r = tid >> 3;            // sorted row within tile, 0..63
  const int c = tid & 7;             // chunk group
  const int p = blockIdx.x * 64 + r;
  if (p >= meta[12]) return;
  const int rid = perm[p];
  char* xt = (char*)(Xs + (size_t)blockIdx.x * 8192);
  #pragma unroll
  for (int q = 0; q < 2; ++q) {
    int cc = c + q * 8;              // 16B-chunk index 0..15 (8 bf16)
    short8 u = {0, 0, 0, 0, 0, 0, 0, 0};
    if (rid >= 0) {
      const float* src = X + (size_t)rid * 128 + cc * 8;
      float4 v0 = *(const float4*)(src);
      float4 v1 = *(const float4*)(src + 4);
      u[0] = (short)f2bf(v0.x); u[1] = (short)f2bf(v0.y);
      u[2] = (short)f2bf(v0.z); u[3] = (short)f2bf(v0.w);
      u[4] = (short)f2bf(v1.x); u[5] = (short)f2bf(v1.y);
      u[6] = (short)f2bf(v1.z); u[7] = (short)f2bf(v1.w);
    }
    int byte = (r * 256 + cc * 16) ^ ((r & 7) << 4);
    *(short8*)(xt + byte) = u;
  }
}

// Weights-stationary persistent MLP. Grid = 512 blocks (2/CU), 128 blocks/type.
// Block handles tiles g0+lb, g0+lb+128, ... of its type. Per-wave W1/W2
// fragment slices live in registers across the whole tile loop.
// Per tile: x staged by global_load_lds (dbuf, counted vmcnt, raw s_barrier),
// layer1 -> h(LDS bf16) -> layer2 -> out transpose via LDS -> row-coalesced store.
__global__ __launch_bounds__(512, 2) void k_mlpw(
    const unsigned short* __restrict__ Xs, const int* __restrict__ perm,
    const int* __restrict__ meta,
    const unsigned short* __restrict__ W1T, const unsigned short* __restrict__ W2T,
    const float* __restrict__ B1, const float* __restrict__ B2,
    float* __restrict__ OUT, float* __restrict__ dump) {
  __shared__ __align__(16) unsigned char x_lds[2][16384];  // dbuf x tile (bf16, swizzled)
  __shared__ __align__(16) unsigned char h_lds[32768];     // h bf16 tile; reused as out f32 tile

  const int tid = threadIdx.x;
  const int l  = tid & 63, w = tid >> 6;   // wave 0..7
  const int lo = l & 15,  hi = l >> 4;

  const int t  = blockIdx.x >> 7;          // 128 blocks per type
  const int lb = blockIdx.x & 127;
  const int g0 = meta[8 + t] >> 6;         // first tile of this type
  const int g1 = meta[9 + t] >> 6;         // one past last
  const int nt = g1 - g0 - lb;
  if (nt <= 0) return;
  const int cnt = (nt + 127) >> 7;

  // ---- stage first tile (2 x global_load_lds width-16 per thread) ----
  {
    const unsigned short* s0 = Xs + (size_t)(g0 + lb) * 8192 + w * 512 + l * 8;
    __builtin_amdgcn_global_load_lds(
        (const __attribute__((address_space(1))) unsigned int*)s0,
        (__attribute__((address_space(3))) unsigned int*)(&x_lds[0][0] + w * 1024), 16, 0, 0);
    __builtin_amdgcn_global_load_lds(
        (const __attribute__((address_space(1))) unsigned int*)(s0 + 4096),
        (__attribute__((address_space(3))) unsigned int*)(&x_lds[0][0] + 8192 + w * 1024), 16, 0, 0);
  }

  // ---- weights + biases into registers, once per block ----
  const unsigned short* w1t = W1T + (t << 15);
  const unsigned short* w2t = W2T + (t << 15);
  short8 a1[4][2], a2[8];
  #pragma unroll
  for (int ks = 0; ks < 4; ++ks)
    #pragma unroll
    for (int m = 0; m < 2; ++m)
      a1[ks][m] = *(const short8*)(w1t + (w * 32 + m * 16 + lo) * 128 + ks * 32 + hi * 8);
  #pragma unroll
  for (int ks = 0; ks < 8; ++ks)
    a2[ks] = *(const short8*)(w2t + (w * 16 + lo) * 256 + ks * 32 + hi * 8);
  f32x4 bb1[2], bb2;
  #pragma unroll
  for (int m = 0; m < 2; ++m)
    bb1[m] = *(const f32x4*)(B1 + t * 256 + w * 32 + m * 16 + hi * 4);
  bb2 = *(const f32x4*)(B2 + t * 128 + w * 16 + hi * 4);

  for (int j = 0; j < cnt; ++j) {
    const int g = g0 + lb + j * 128;
    const bool hn = (j + 1 < cnt);

    // issue next tile's stage before waiting on current (keeps HBM busy)
    if (hn) {
      const unsigned short* s0 = Xs + (size_t)(g + 128) * 8192 + w * 512 + l * 8;
      unsigned char* d0 = &x_lds[(j + 1) & 1][0];
      __builtin_amdgcn_global_load_lds(
          (const __attribute__((address_space(1))) unsigned int*)s0,
          (__attribute__((address_space(3))) unsigned int*)(d0 + w * 1024), 16, 0, 0);
      __builtin_amdgcn_global_load_lds(
          (const __attribute__((address_space(1))) unsigned int*)(s0 + 4096),
          (__attribute__((address_space(3))) unsigned int*)(d0 + 8192 + w * 1024), 16, 0, 0);
    }

    // counted vmcnt: guarantee tile-j x-loads retired (in-order retirement).
    // newer-than-tile-j ops: j==0: {next 2}; j>0: {rid 4, stores 4, next 2}.
    if (j == 0) {
      if (hn) asm volatile("s_waitcnt vmcnt(2)" ::: "memory");
      else    asm volatile("s_waitcnt vmcnt(0)" ::: "memory");
    } else {
      if (hn) asm volatile("s_waitcnt vmcnt(10)" ::: "memory");
      else    asm volatile("s_waitcnt vmcnt(8)" ::: "memory");
    }
    __builtin_amdgcn_s_barrier();
    __builtin_amdgcn_sched_barrier(0);

    const unsigned char* xb = &x_lds[j & 1][0];

    // ---- layer 1: W1 frags in regs (A), x from LDS (B) ----
    f32x4 acc[2][4];
    #pragma unroll
    for (int m = 0; m < 2; ++m)
      #pragma unroll
      for (int n = 0; n < 4; ++n) acc[m][n] = (f32x4){0.f, 0.f, 0.f, 0.f};
    #pragma unroll
    for (int ks = 0; ks < 4; ++ks) {
      const int k8 = ks * 32 + hi * 8;
      short8 b[4];
      #pragma unroll
      for (int n = 0; n < 4; ++n) {
        int row = n * 16 + lo;
        int byte = (row * 256 + k8 * 2) ^ ((row & 7) << 4);
        b[n] = *(const short8*)(xb + byte);
      }
      #pragma unroll
      for (int m = 0; m < 2; ++m)
        #pragma unroll
        for (int n = 0; n < 4; ++n)
          acc[m][n] = __builtin_amdgcn_mfma_f32_16x16x32_bf16(a1[ks][m], b[n], acc[m][n], 0, 0, 0);
    }

    // bias + relu -> h LDS (lane owns 4 consecutive hcols -> b64 writes)
    #pragma unroll
    for (int m = 0; m < 2; ++m) {
      const int hc = w * 32 + m * 16 + hi * 4;
      #pragma unroll
      for (int n = 0; n < 4; ++n) {
        int row = n * 16 + lo;
        ushort4 hv;
        hv.x = f2bf(fmaxf(acc[m][n][0] + bb1[m][0], 0.f));
        hv.y = f2bf(fmaxf(acc[m][n][1] + bb1[m][1], 0.f));
        hv.z = f2bf(fmaxf(acc[m][n][2] + bb1[m][2], 0.f));
        hv.w = f2bf(fmaxf(acc[m][n][3] + bb1[m][3], 0.f));
        int byte = (row * 512 + hc * 2) ^ ((row & 7) << 4);
        *(ushort4*)(h_lds + byte) = hv;
      }
    }
    LGKM_BAR();

    // ---- layer 2: W2 frags in regs (A), h from LDS (B) ----
    f32x4 acc2[4];
    #pragma unroll
    for (int n = 0; n < 4; ++n) acc2[n] = (f32x4){0.f, 0.f, 0.f, 0.f};
    #pragma unroll
    for (int ks = 0; ks < 8; ++ks) {
      const int k8 = ks * 32 + hi * 8;
      short8 b[4];
      #pragma unroll
      for (int n = 0; n < 4; ++n) {
        int row = n * 16 + lo;
        int byte = (row * 512 + k8 * 2) ^ ((row & 7) << 4);
        b[n] = *(const short8*)(h_lds + byte);
      }
      #pragma unroll
      for (int n = 0; n < 4; ++n)
        acc2[n] = __builtin_amdgcn_mfma_f32_16x16x32_bf16(a2[ks], b[n], acc2[n], 0, 0, 0);
    }

    // rowids for the store phase (4 per thread, always issued)
    int rid[4];
    #pragma unroll
    for (int p = 0; p < 4; ++p) rid[p] = perm[g * 64 + p * 16 + (tid >> 5)];

    LGKM_BAR();   // all h reads done -> safe to overwrite h_lds with out f32

    // out f32 -> LDS (lane owns 4 consecutive ocols, swizzled rows)
    #pragma unroll
    for (int n = 0; n < 4; ++n) {
      int row = n * 16 + lo;
      const int oc = w * 16 + hi * 4;
      f32x4 o = acc2[n];
      o[0] += bb2[0]; o[1] += bb2[1]; o[2] += bb2[2]; o[3] += bb2[3];
      int byte = (row * 512 + oc * 4) ^ ((row & 7) << 4);
      *(f32x4*)(h_lds + byte) = o;
    }
    LGKM_BAR();   // out tile visible

    // row-coalesced scatter: 32 consecutive lanes write one contiguous 512B row
    #pragma unroll
    for (int p = 0; p < 4; ++p) {
      int off = p * 8192 + tid * 16;
      int row = off >> 9;
      f32x4 v = *(const f32x4*)(h_lds + (off ^ ((row & 7) << 4)));
      int colf = (off & 511) >> 2;
      float* dst = (rid[p] >= 0) ? (OUT + (size_t)rid[p] * 128 + colf) : (dump + colf);
      *(f32x4*)dst = v;   // always 4 stores/thread: keeps vmcnt accounting exact
    }
  }
}

extern "C" void kernel_launch(void* const* d_in, const int* in_sizes, int n_in,
                              void* d_out, int out_size, void* d_ws, size_t ws_size,
                              hipStream_t stream) {
  const float* X  = (const float*)d_in[0];
  const int*   NT = (const int*)d_in[1];
  const float* W1 = (const float*)d_in[2];
  const float* B1 = (const float*)d_in[3];
  const float* W2 = (const float*)d_in[4];
  const float* B2 = (const float*)d_in[5];
  float* OUT = (float*)d_out;
  const int n = in_sizes[1];

  char* ws = (char*)d_ws;
  int* meta = (int*)ws;                                   // counts/cursors/bases
  float* dump = (float*)(ws + 512);
  int* perm = (int*)(ws + 1024);
  unsigned short* W1T = (unsigned short*)(ws + 402432);
  unsigned short* W2T = (unsigned short*)(ws + 664576);
  unsigned short* Xs  = (unsigned short*)(ws + 1048576);

  const int ntiles = (n + 63) / 64 + NTYPES;              // worst-case padded tiles

  hipMemsetAsync(ws, 0, 64, stream);                      // counts + cursors = 0

  k_prep<<<512, 256, 0, stream>>>(W1, W2, W1T, W2T);
  const int nb = (n + 255) / 256;
  k_hist<<<nb, 256, 0, stream>>>(NT, n, meta);
  k_scatter<<<nb, 256, 0, stream>>>(NT, n, meta, perm);
  k_sort<<<ntiles, 512, 0, stream>>>(X, perm, meta, Xs);
  k_mlpw<<<512, 512, 0, stream>>>(Xs, perm, meta, W1T, W2T, B1, B2, OUT, dump);
}